// Round 7
// baseline (554.468 us; speedup 1.0000x reference)
//
#include <hip/hip_runtime.h>
#include <math.h>

#define NB     32
#define NA     1024
#define NEIGH  64
#define NTYPE  4
#define NWAVE  16
#define PPB    (NA * NEIGH)        // 65536 pairs per batch
#define NPAIRS (NB * PPB)          // 2,097,152 pairs
#define TOTATOM (NB * NA)          // 32768
#define DENS_ELEMS (TOTATOM * NTYPE * NWAVE)  // 2,097,152 floats (== out_size)
#define CUTOFF_INV (1.0f / 5.0f)
#define PI_F 3.14159265358979323846f

#define NSPLIT 8                   // blocks per batch
#define BLOCK  1024                // 16 waves/block
#define PAIRS_PER_BLOCK (PPB / NSPLIT)   // 8192
#define KITERS (PAIRS_PER_BLOCK / BLOCK) // 8
#define WS_NEEDED ((size_t)NB * NSPLIT * NA * NWAVE * sizeof(float))  // 16 MiB

// Compiler-visible native LDS float atomic add (AS(3) atomicrmw fadd).
typedef __attribute__((address_space(3))) float lds_float;
__device__ __forceinline__ void lds_fadd(float* p, float v) {
    lds_float* lp = (lds_float*)(unsigned)(unsigned long long)p;
    __atomic_fetch_add(lp, v, __ATOMIC_RELAXED);
}

// Common per-pair math. Produces r, spec-row float4s, lfc.
#define PAIR_MATH_PROLOG(CB_X, CB_Y, CB_Z, SPEC_LOAD)                         \
    const int pp = k * BLOCK + tid;                                           \
    const int i = ai0[pp];                                                    \
    const int j = ai1[pp];                                                    \
    const float sx = shb[pp * 3 + 0];                                         \
    const float sy = shb[pp * 3 + 1];                                         \
    const float sz = shb[pp * 3 + 2];                                         \
    const bool valid = (sx > -1e9f) && (sy > -1e9f) && (sz > -1e9f);          \
    const float dx = (CB_X(i)) - (CB_X(j)) + sx;                              \
    const float dy = (CB_Y(i)) - (CB_Y(j)) + sy;                              \
    const float dz = (CB_Z(i)) - (CB_Z(j)) + sz;                              \
    const float r  = sqrtf(dx * dx + dy * dy + dz * dz);                      \
    const int spec = (SPEC_LOAD);                                             \
    float x  = fminf(r * CUTOFF_INV, 1.0f);                                   \
    float fc = 0.5f * (__cosf(x * PI_F) + 1.0f);                              \
    fc = fmaxf(fc, 0.0f);                                                     \
    if (!valid) fc = 0.0f;                                                    \
    const float lfc = __logf(fc);                                             \
    const float4* r4 = reinterpret_cast<const float4*>(srs   + (spec << 4));  \
    const float4* a4 = reinterpret_cast<const float4*>(sinta + (spec << 4));  \
    const float4 R0 = r4[0], R1 = r4[1], R2 = r4[2], R3 = r4[3];              \
    const float4 A0 = a4[0], A1 = a4[1], A2 = a4[2], A3 = a4[3];

#define ALL_W(DO_W)                                                            \
    DO_W(0,  R0.x, A0.x) DO_W(1,  R0.y, A0.y) DO_W(2,  R0.z, A0.z) DO_W(3,  R0.w, A0.w) \
    DO_W(4,  R1.x, A1.x) DO_W(5,  R1.y, A1.y) DO_W(6,  R1.z, A1.z) DO_W(7,  R1.w, A1.w) \
    DO_W(8,  R2.x, A2.x) DO_W(9,  R2.y, A2.y) DO_W(10, R2.z, A2.z) DO_W(11, R2.w, A2.w) \
    DO_W(12, R3.x, A3.x) DO_W(13, R3.y, A3.y) DO_W(14, R3.z, A3.z) DO_W(15, R3.w, A3.w)

// ---------------------------------------------------------------------------
// V4 (REAL): coords + species staged in LDS; gathers become ds_reads.
// ---------------------------------------------------------------------------
__global__ __launch_bounds__(BLOCK) void radial_pair_staged(
    const float* __restrict__ coords, const float* __restrict__ shifts,
    const float* __restrict__ rs, const float* __restrict__ inta,
    const int* __restrict__ atom_index, const int* __restrict__ species,
    float* __restrict__ part)
{
    __shared__ float sdens[NA * NWAVE];    // 64 KiB
    __shared__ float scoord[NA * 3];       // 12 KiB, stride-3 (32-bank spread)
    __shared__ int   sspec[NA];            // 4 KiB
    __shared__ float srs[NTYPE * NWAVE];
    __shared__ float sinta[NTYPE * NWAVE];

    const int b   = blockIdx.x >> 3;
    const int s   = blockIdx.x & (NSPLIT - 1);
    const int tid = threadIdx.x;

    const float* cb = coords  + (size_t)b * NA * 3;
    const int*   sb = species + b * NA;

    if (tid < NTYPE * NWAVE) {
        srs[tid]   = rs[tid];
        sinta[tid] = -10.0f * inta[tid];
    }
    #pragma unroll
    for (int k = 0; k < 3; ++k)
        scoord[k * BLOCK + tid] = cb[k * BLOCK + tid];
    sspec[tid] = sb[tid];
    {
        float4* z4 = reinterpret_cast<float4*>(sdens);
        #pragma unroll
        for (int k = 0; k < (NA * NWAVE / 4) / BLOCK; ++k)
            z4[k * BLOCK + tid] = make_float4(0.f, 0.f, 0.f, 0.f);
    }
    __syncthreads();

    const int* ai0 = atom_index + (b * 2 + 0) * PPB + s * PAIRS_PER_BLOCK;
    const int* ai1 = atom_index + (b * 2 + 1) * PPB + s * PAIRS_PER_BLOCK;
    const float* shb = shifts + ((size_t)b * PPB + s * PAIRS_PER_BLOCK) * 3;

    #define CBX(a) scoord[(a) * 3 + 0]
    #define CBY(a) scoord[(a) * 3 + 1]
    #define CBZ(a) scoord[(a) * 3 + 2]
    #pragma unroll 2
    for (int k = 0; k < KITERS; ++k) {
        PAIR_MATH_PROLOG(CBX, CBY, CBZ, sspec[i])
        float* drow = sdens + (i << 4);
        const int rot = i & (NWAVE - 1);
        #define DO_W(w, RS, IA)                                           \
        {                                                                 \
            const float d   = r - (RS);                                   \
            const float arg = fmaf((IA) * d, d, lfc);                     \
            lds_fadd(drow + (((w) + rot) & (NWAVE - 1)), __expf(arg));    \
        }
        ALL_W(DO_W)
        #undef DO_W
    }
    #undef CBX
    #undef CBY
    #undef CBZ
    __syncthreads();

    float* dst = part + ((size_t)(b * NSPLIT + s)) * (NA * NWAVE);
    #pragma unroll
    for (int k = 0; k < (NA * NWAVE) / BLOCK; ++k) {
        const int f = k * BLOCK + tid;
        const int a = f >> 4;
        const int w = f & (NWAVE - 1);
        dst[f] = sdens[(a << 4) + ((w + a) & (NWAVE - 1))];
    }
}

// ---------------------------------------------------------------------------
// V0 (ablation control): round-6 kernel verbatim — global gathers + atomics.
// ---------------------------------------------------------------------------
__global__ __launch_bounds__(BLOCK) void ablate_v0(
    const float* __restrict__ coords, const float* __restrict__ shifts,
    const float* __restrict__ rs, const float* __restrict__ inta,
    const int* __restrict__ atom_index, const int* __restrict__ species,
    float* __restrict__ part)
{
    __shared__ float sdens[NA * NWAVE];
    __shared__ float srs[NTYPE * NWAVE];
    __shared__ float sinta[NTYPE * NWAVE];

    const int b   = blockIdx.x >> 3;
    const int s   = blockIdx.x & (NSPLIT - 1);
    const int tid = threadIdx.x;

    if (tid < NTYPE * NWAVE) {
        srs[tid]   = rs[tid];
        sinta[tid] = -10.0f * inta[tid];
    }
    {
        float4* z4 = reinterpret_cast<float4*>(sdens);
        #pragma unroll
        for (int k = 0; k < (NA * NWAVE / 4) / BLOCK; ++k)
            z4[k * BLOCK + tid] = make_float4(0.f, 0.f, 0.f, 0.f);
    }
    __syncthreads();

    const int* ai0 = atom_index + (b * 2 + 0) * PPB + s * PAIRS_PER_BLOCK;
    const int* ai1 = atom_index + (b * 2 + 1) * PPB + s * PAIRS_PER_BLOCK;
    const float* cb = coords  + (size_t)b * NA * 3;
    const int*   sb = species + b * NA;
    const float* shb = shifts + ((size_t)b * PPB + s * PAIRS_PER_BLOCK) * 3;

    #define CBX(a) cb[(a) * 3 + 0]
    #define CBY(a) cb[(a) * 3 + 1]
    #define CBZ(a) cb[(a) * 3 + 2]
    #pragma unroll 2
    for (int k = 0; k < KITERS; ++k) {
        PAIR_MATH_PROLOG(CBX, CBY, CBZ, sb[i])
        float* drow = sdens + (i << 4);
        const int rot = i & (NWAVE - 1);
        #define DO_W(w, RS, IA)                                           \
        {                                                                 \
            const float d   = r - (RS);                                   \
            const float arg = fmaf((IA) * d, d, lfc);                     \
            lds_fadd(drow + (((w) + rot) & (NWAVE - 1)), __expf(arg));    \
        }
        ALL_W(DO_W)
        #undef DO_W
    }
    #undef CBX
    #undef CBY
    #undef CBZ
    __syncthreads();

    float* dst = part + ((size_t)(b * NSPLIT + s)) * (NA * NWAVE);
    #pragma unroll
    for (int k = 0; k < (NA * NWAVE) / BLOCK; ++k) {
        const int f = k * BLOCK + tid;
        const int a = f >> 4;
        const int w = f & (NWAVE - 1);
        dst[f] = sdens[(a << 4) + ((w + a) & (NWAVE - 1))];
    }
}

// ---------------------------------------------------------------------------
// Ablation: same loads + math, NO atomics (register accumulate + asm sink).
// ---------------------------------------------------------------------------
__global__ __launch_bounds__(BLOCK) void ablate_noatomic(
    const float* __restrict__ coords, const float* __restrict__ shifts,
    const float* __restrict__ rs, const float* __restrict__ inta,
    const int* __restrict__ atom_index, const int* __restrict__ species,
    float* __restrict__ part)
{
    __shared__ float sdens[NA * NWAVE];
    __shared__ float srs[NTYPE * NWAVE];
    __shared__ float sinta[NTYPE * NWAVE];

    const int b   = blockIdx.x >> 3;
    const int s   = blockIdx.x & (NSPLIT - 1);
    const int tid = threadIdx.x;

    if (tid < NTYPE * NWAVE) {
        srs[tid]   = rs[tid];
        sinta[tid] = -10.0f * inta[tid];
    }
    {
        float4* z4 = reinterpret_cast<float4*>(sdens);
        #pragma unroll
        for (int k = 0; k < (NA * NWAVE / 4) / BLOCK; ++k)
            z4[k * BLOCK + tid] = make_float4(0.f, 0.f, 0.f, 0.f);
    }
    __syncthreads();

    const int* ai0 = atom_index + (b * 2 + 0) * PPB + s * PAIRS_PER_BLOCK;
    const int* ai1 = atom_index + (b * 2 + 1) * PPB + s * PAIRS_PER_BLOCK;
    const float* cb = coords  + (size_t)b * NA * 3;
    const int*   sb = species + b * NA;
    const float* shb = shifts + ((size_t)b * PPB + s * PAIRS_PER_BLOCK) * 3;

    #define CBX(a) cb[(a) * 3 + 0]
    #define CBY(a) cb[(a) * 3 + 1]
    #define CBZ(a) cb[(a) * 3 + 2]
    #pragma unroll 2
    for (int k = 0; k < KITERS; ++k) {
        PAIR_MATH_PROLOG(CBX, CBY, CBZ, sb[i])
        float acc = 0.0f;
        #define DO_W(w, RS, IA)                                           \
        {                                                                 \
            const float d   = r - (RS);                                   \
            const float arg = fmaf((IA) * d, d, lfc);                     \
            acc += __expf(arg);                                           \
        }
        ALL_W(DO_W)
        #undef DO_W
        asm volatile("" :: "v"(acc));   // keep math live (rule #17)
    }
    #undef CBX
    #undef CBY
    #undef CBZ
    __syncthreads();

    float* dst = part + ((size_t)(b * NSPLIT + s)) * (NA * NWAVE);
    #pragma unroll
    for (int k = 0; k < (NA * NWAVE) / BLOCK; ++k) {
        const int f = k * BLOCK + tid;
        const int a = f >> 4;
        const int w = f & (NWAVE - 1);
        dst[f] = sdens[(a << 4) + ((w + a) & (NWAVE - 1))];
    }
}

// ---------------------------------------------------------------------------
// Ablation: same loads + math, atomics to PRIVATE conflict-free slots
// (slot = w*1024 + tid: consecutive lanes -> consecutive banks, no collisions).
// ---------------------------------------------------------------------------
__global__ __launch_bounds__(BLOCK) void ablate_privatomic(
    const float* __restrict__ coords, const float* __restrict__ shifts,
    const float* __restrict__ rs, const float* __restrict__ inta,
    const int* __restrict__ atom_index, const int* __restrict__ species,
    float* __restrict__ part)
{
    __shared__ float sdens[NA * NWAVE];
    __shared__ float srs[NTYPE * NWAVE];
    __shared__ float sinta[NTYPE * NWAVE];

    const int b   = blockIdx.x >> 3;
    const int s   = blockIdx.x & (NSPLIT - 1);
    const int tid = threadIdx.x;

    if (tid < NTYPE * NWAVE) {
        srs[tid]   = rs[tid];
        sinta[tid] = -10.0f * inta[tid];
    }
    {
        float4* z4 = reinterpret_cast<float4*>(sdens);
        #pragma unroll
        for (int k = 0; k < (NA * NWAVE / 4) / BLOCK; ++k)
            z4[k * BLOCK + tid] = make_float4(0.f, 0.f, 0.f, 0.f);
    }
    __syncthreads();

    const int* ai0 = atom_index + (b * 2 + 0) * PPB + s * PAIRS_PER_BLOCK;
    const int* ai1 = atom_index + (b * 2 + 1) * PPB + s * PAIRS_PER_BLOCK;
    const float* cb = coords  + (size_t)b * NA * 3;
    const int*   sb = species + b * NA;
    const float* shb = shifts + ((size_t)b * PPB + s * PAIRS_PER_BLOCK) * 3;

    #define CBX(a) cb[(a) * 3 + 0]
    #define CBY(a) cb[(a) * 3 + 1]
    #define CBZ(a) cb[(a) * 3 + 2]
    #pragma unroll 2
    for (int k = 0; k < KITERS; ++k) {
        PAIR_MATH_PROLOG(CBX, CBY, CBZ, sb[i])
        #define DO_W(w, RS, IA)                                           \
        {                                                                 \
            const float d   = r - (RS);                                   \
            const float arg = fmaf((IA) * d, d, lfc);                     \
            lds_fadd(sdens + ((w) << 10) + tid, __expf(arg));             \
        }
        ALL_W(DO_W)
        #undef DO_W
    }
    #undef CBX
    #undef CBY
    #undef CBZ
    __syncthreads();

    float* dst = part + ((size_t)(b * NSPLIT + s)) * (NA * NWAVE);
    #pragma unroll
    for (int k = 0; k < (NA * NWAVE) / BLOCK; ++k) {
        const int f = k * BLOCK + tid;
        const int a = f >> 4;
        const int w = f & (NWAVE - 1);
        dst[f] = sdens[(a << 4) + ((w + a) & (NWAVE - 1))];
    }
}

// Sum partials, square, write full output row (zeros for unused type rows).
__global__ __launch_bounds__(256) void reduce_square(
    const float* __restrict__ part,
    const int*   __restrict__ species,
    float*       __restrict__ out)
{
    const int t = blockIdx.x * blockDim.x + threadIdx.x;
    if (t >= TOTATOM * NWAVE) return;
    const int g = t >> 4;
    const int w = t & (NWAVE - 1);
    const int b = g >> 10;
    const int a = g & (NA - 1);

    const float* p = part + ((size_t)b * NSPLIT) * (NA * NWAVE) + a * NWAVE + w;
    float sum = 0.0f;
    #pragma unroll
    for (int s = 0; s < NSPLIT; ++s)
        sum += p[(size_t)s * NA * NWAVE];
    sum *= sum;

    const int spec = species[g];
    float* o = out + (size_t)g * (NTYPE * NWAVE) + w;
    #pragma unroll
    for (int ty = 0; ty < NTYPE; ++ty)
        o[ty * NWAVE] = (ty == spec) ? sum : 0.0f;
}

// Fallback path (ws too small): global-atomic version.
__global__ __launch_bounds__(256) void radial_pair_atomic(
    const float* __restrict__ coords, const float* __restrict__ shifts,
    const float* __restrict__ rs, const float* __restrict__ inta,
    const int* __restrict__ atom_index, const int* __restrict__ species,
    float* __restrict__ dens)
{
    int p = blockIdx.x * blockDim.x + threadIdx.x;
    if (p >= NPAIRS) return;
    int b  = p >> 16;
    int pp = p & (PPB - 1);
    int i = atom_index[(b * 2 + 0) * PPB + pp] + b * NA;
    int j = atom_index[(b * 2 + 1) * PPB + pp] + b * NA;
    float sx = shifts[p * 3 + 0], sy = shifts[p * 3 + 1], sz = shifts[p * 3 + 2];
    bool valid = (sx > -1e9f) && (sy > -1e9f) && (sz > -1e9f);
    float dx = coords[i * 3 + 0] - coords[j * 3 + 0] + sx;
    float dy = coords[i * 3 + 1] - coords[j * 3 + 1] + sy;
    float dz = coords[i * 3 + 2] - coords[j * 3 + 2] + sz;
    float r  = sqrtf(dx * dx + dy * dy + dz * dz);
    int spec = species[i];
    float x  = fminf(r * CUTOFF_INV, 1.0f);
    float fc = 0.5f * (__cosf(x * PI_F) + 1.0f);
    if (!valid) fc = 0.0f;
    const float* rsrow   = rs   + spec * NWAVE;
    const float* intarow = inta + spec * NWAVE;
    float* dst = dens + ((size_t)i * NTYPE + spec) * NWAVE;
    #pragma unroll
    for (int w = 0; w < NWAVE; ++w) {
        float d   = r - rsrow[w];
        float val = fc * __expf(-10.0f * intarow[w] * d * d);
        atomicAdd(dst + w, val);
    }
}

__global__ __launch_bounds__(256) void square_kernel(float* __restrict__ out)
{
    int i = blockIdx.x * blockDim.x + threadIdx.x;
    if (i * 4 >= DENS_ELEMS) return;
    float4* p = reinterpret_cast<float4*>(out) + i;
    float4 v = *p;
    v.x *= v.x; v.y *= v.y; v.z *= v.z; v.w *= v.w;
    *p = v;
}

extern "C" void kernel_launch(void* const* d_in, const int* in_sizes, int n_in,
                              void* d_out, int out_size, void* d_ws, size_t ws_size,
                              hipStream_t stream) {
    const float* coords     = (const float*)d_in[0];
    const float* shifts     = (const float*)d_in[1];
    const float* rs         = (const float*)d_in[2];
    const float* inta       = (const float*)d_in[3];
    const int*   atom_index = (const int*)d_in[6];
    const int*   species    = (const int*)d_in[7];
    float* out = (float*)d_out;

    if (ws_size >= WS_NEEDED) {
        float* part = (float*)d_ws;
        // REAL pipeline first: staged-LDS pair kernel, then reduce.
        radial_pair_staged<<<dim3(NB * NSPLIT), dim3(BLOCK), 0, stream>>>(
            coords, shifts, rs, inta, atom_index, species, part);
        reduce_square<<<dim3((TOTATOM * NWAVE + 255) / 256), dim3(256), 0, stream>>>(
            part, species, out);
        // Ablation probes (clobber part AFTER it has been consumed; output
        // already written -> deterministic d_out regardless).
        ablate_v0<<<dim3(NB * NSPLIT), dim3(BLOCK), 0, stream>>>(
            coords, shifts, rs, inta, atom_index, species, part);
        ablate_noatomic<<<dim3(NB * NSPLIT), dim3(BLOCK), 0, stream>>>(
            coords, shifts, rs, inta, atom_index, species, part);
        ablate_privatomic<<<dim3(NB * NSPLIT), dim3(BLOCK), 0, stream>>>(
            coords, shifts, rs, inta, atom_index, species, part);
    } else {
        hipMemsetAsync(d_out, 0, (size_t)DENS_ELEMS * sizeof(float), stream);
        radial_pair_atomic<<<dim3((NPAIRS + 255) / 256), dim3(256), 0, stream>>>(
            coords, shifts, rs, inta, atom_index, species, out);
        square_kernel<<<dim3((DENS_ELEMS / 4 + 255) / 256), dim3(256), 0, stream>>>(out);
    }
}

// Round 8
// 67.759 us; speedup vs baseline: 8.1830x; 8.1830x over previous
//
#include <hip/hip_runtime.h>
#include <math.h>

// Problem constants (fixed by the reference setup)
#define NB     32
#define NA     1024
#define NTYPE  4
#define NWAVE  16
#define PPB    65536               // pairs per batch
#define NPAIRS (NB * PPB)          // 2,097,152 pairs
#define TOTATOM (NB * NA)          // 32768
#define DENS_ELEMS (TOTATOM * NTYPE * NWAVE)  // == out_size
#define CUTOFF      5.0f
#define CUTOFF_INV  0.2f
#define PI_F 3.14159265358979323846f

#define NSPLIT 8                   // bin blocks per batch
#define BLOCK_A 1024
#define PAIRS_PER_BLOCK (PPB / NSPLIT)      // 8192
#define KITERS_A (PAIRS_PER_BLOCK / BLOCK_A) // 8
#define CAP 30                     // bucket slots per (batch,split,atom); λ≈7.7
#define ENC_SCALE (65535.0f / CUTOFF)
#define DEC_SCALE (CUTOFF / 65535.0f)

#define BUCKET_U16S ((size_t)TOTATOM * NSPLIT * CAP)        // 7,864,320
#define BUCKET_BYTES (BUCKET_U16S * 2)                      // 15,728,640
#define COUNT_BYTES  ((size_t)TOTATOM * NSPLIT)             // 262,144 (8B-aligned base)
#define WS2_NEEDED   (BUCKET_BYTES + COUNT_BYTES)           // 15,990,784 < 16 MiB

// Compiler-visible native LDS u32 atomic add (AS(3) atomicrmw).
typedef __attribute__((address_space(3))) unsigned lds_u32;
__device__ __forceinline__ unsigned lds_uinc(unsigned* p) {
    lds_u32* lp = (lds_u32*)(unsigned)(unsigned long long)p;
    return __atomic_fetch_add(lp, 1u, __ATOMIC_RELAXED);
}

// ---------------------------------------------------------------------------
// Phase A: per (batch, split) block. Compute r once per pair; 1 LDS int atomic
// per surviving pair reserves a bucket slot; write u16-quantized r.
// ---------------------------------------------------------------------------
__global__ __launch_bounds__(BLOCK_A) void radial_bin(
    const float* __restrict__ coords,      // [TOTATOM*3]
    const float* __restrict__ shifts,      // [NPAIRS*3]
    const int*   __restrict__ atom_index,  // [NB*2*PPB]
    unsigned short* __restrict__ bucket,   // [TOTATOM][NSPLIT][CAP]
    unsigned char*  __restrict__ counts)   // [TOTATOM][NSPLIT]
{
    __shared__ unsigned hist[NA];

    const int b   = blockIdx.x >> 3;       // / NSPLIT
    const int s   = blockIdx.x & (NSPLIT - 1);
    const int tid = threadIdx.x;

    hist[tid] = 0u;
    __syncthreads();

    const int* ai0 = atom_index + (b * 2 + 0) * PPB + s * PAIRS_PER_BLOCK;
    const int* ai1 = atom_index + (b * 2 + 1) * PPB + s * PAIRS_PER_BLOCK;
    const float* cb  = coords + (size_t)b * NA * 3;
    const float* shb = shifts + ((size_t)b * PPB + s * PAIRS_PER_BLOCK) * 3;

    #pragma unroll 2
    for (int k = 0; k < KITERS_A; ++k) {
        const int pp = k * BLOCK_A + tid;
        const int i = ai0[pp];
        const int j = ai1[pp];

        const float sx = shb[pp * 3 + 0];
        const float sy = shb[pp * 3 + 1];
        const float sz = shb[pp * 3 + 2];
        const bool valid = (sx > -1e9f) && (sy > -1e9f) && (sz > -1e9f);

        const float dx = cb[i * 3 + 0] - cb[j * 3 + 0] + sx;
        const float dy = cb[i * 3 + 1] - cb[j * 3 + 1] + sy;
        const float dz = cb[i * 3 + 2] - cb[j * 3 + 2] + sz;
        const float r  = sqrtf(dx * dx + dy * dy + dz * dz);

        // r >= CUTOFF -> fc == 0 (ref value ~1e-15): drop. invalid -> drop.
        if (valid && r < CUTOFF) {
            const unsigned slot = lds_uinc(&hist[i]);
            if (slot < CAP) {
                unsigned e = (unsigned)(r * ENC_SCALE + 0.5f);
                if (e > 65535u) e = 65535u;
                bucket[((size_t)(b * NA + i) * NSPLIT + s) * CAP + slot] =
                    (unsigned short)e;
            }
        }
    }
    __syncthreads();

    unsigned c = hist[tid];
    counts[(size_t)(b * NA + tid) * NSPLIT + s] =
        (unsigned char)(c < CAP ? c : CAP);
}

// ---------------------------------------------------------------------------
// Phase B: thread = (atom, w-quad). Register accumulation over the atom's
// bucket entries; square; write the full 64-float output row. No atomics.
// ---------------------------------------------------------------------------
__global__ __launch_bounds__(256) void radial_gather(
    const unsigned short* __restrict__ bucket,  // [TOTATOM][NSPLIT][CAP]
    const unsigned char*  __restrict__ counts,  // [TOTATOM][NSPLIT]
    const float* __restrict__ rs,               // [NTYPE*NWAVE]
    const float* __restrict__ inta,             // [NTYPE*NWAVE]
    const int*   __restrict__ species,          // [TOTATOM]
    float*       __restrict__ out)              // [TOTATOM][NTYPE*NWAVE]
{
    const int t = blockIdx.x * blockDim.x + threadIdx.x;
    if (t >= TOTATOM * 4) return;
    const int g = t >> 2;              // global atom
    const int q = t & 3;               // w-quad (w = q*4 .. q*4+3)

    const int spec = species[g];

    const float4 RS = *reinterpret_cast<const float4*>(rs   + (spec << 4) + (q << 2));
    const float4 IAv = *reinterpret_cast<const float4*>(inta + (spec << 4) + (q << 2));
    const float ia0 = -10.0f * IAv.x, ia1 = -10.0f * IAv.y;
    const float ia2 = -10.0f * IAv.z, ia3 = -10.0f * IAv.w;

    const unsigned long long cnt8 =
        *reinterpret_cast<const unsigned long long*>(counts + (size_t)g * NSPLIT);

    float acc0 = 0.0f, acc1 = 0.0f, acc2 = 0.0f, acc3 = 0.0f;

    #pragma unroll
    for (int s = 0; s < NSPLIT; ++s) {
        const int c = (int)((cnt8 >> (8 * s)) & 0xFFull);
        const unsigned short* bp = bucket + ((size_t)g * NSPLIT + s) * CAP;
        for (int k = 0; k < c; ++k) {
            const float r = (float)bp[k] * DEC_SCALE;
            const float x = fminf(r * CUTOFF_INV, 1.0f);
            float fc = 0.5f * (__cosf(x * PI_F) + 1.0f);
            fc = fmaxf(fc, 0.0f);
            const float lfc = __logf(fc);
            const float d0 = r - RS.x;
            const float d1 = r - RS.y;
            const float d2 = r - RS.z;
            const float d3 = r - RS.w;
            acc0 += __expf(fmaf(ia0 * d0, d0, lfc));
            acc1 += __expf(fmaf(ia1 * d1, d1, lfc));
            acc2 += __expf(fmaf(ia2 * d2, d2, lfc));
            acc3 += __expf(fmaf(ia3 * d3, d3, lfc));
        }
    }

    const float4 sq = make_float4(acc0 * acc0, acc1 * acc1,
                                  acc2 * acc2, acc3 * acc3);
    const float4 zero = make_float4(0.f, 0.f, 0.f, 0.f);
    float* orow = out + (size_t)g * (NTYPE * NWAVE) + (q << 2);
    #pragma unroll
    for (int ty = 0; ty < NTYPE; ++ty)
        *reinterpret_cast<float4*>(orow + ty * NWAVE) = (ty == spec) ? sq : zero;
}

// ---------------------------------------------------------------------------
// Fallback path (ws too small): global-atomic version (no workspace needed).
// ---------------------------------------------------------------------------
__global__ __launch_bounds__(256) void radial_pair_atomic(
    const float* __restrict__ coords, const float* __restrict__ shifts,
    const float* __restrict__ rs, const float* __restrict__ inta,
    const int* __restrict__ atom_index, const int* __restrict__ species,
    float* __restrict__ dens)
{
    int p = blockIdx.x * blockDim.x + threadIdx.x;
    if (p >= NPAIRS) return;
    int b  = p >> 16;
    int pp = p & (PPB - 1);
    int i = atom_index[(b * 2 + 0) * PPB + pp] + b * NA;
    int j = atom_index[(b * 2 + 1) * PPB + pp] + b * NA;
    float sx = shifts[p * 3 + 0], sy = shifts[p * 3 + 1], sz = shifts[p * 3 + 2];
    bool valid = (sx > -1e9f) && (sy > -1e9f) && (sz > -1e9f);
    float dx = coords[i * 3 + 0] - coords[j * 3 + 0] + sx;
    float dy = coords[i * 3 + 1] - coords[j * 3 + 1] + sy;
    float dz = coords[i * 3 + 2] - coords[j * 3 + 2] + sz;
    float r  = sqrtf(dx * dx + dy * dy + dz * dz);
    int spec = species[i];
    float x  = fminf(r * CUTOFF_INV, 1.0f);
    float fc = 0.5f * (__cosf(x * PI_F) + 1.0f);
    if (!valid) fc = 0.0f;
    const float* rsrow   = rs   + spec * NWAVE;
    const float* intarow = inta + spec * NWAVE;
    float* dst = dens + ((size_t)i * NTYPE + spec) * NWAVE;
    #pragma unroll
    for (int w = 0; w < NWAVE; ++w) {
        float d   = r - rsrow[w];
        float val = fc * __expf(-10.0f * intarow[w] * d * d);
        atomicAdd(dst + w, val);
    }
}

__global__ __launch_bounds__(256) void square_kernel(float* __restrict__ out)
{
    int i = blockIdx.x * blockDim.x + threadIdx.x;
    if (i * 4 >= DENS_ELEMS) return;
    float4* p = reinterpret_cast<float4*>(out) + i;
    float4 v = *p;
    v.x *= v.x; v.y *= v.y; v.z *= v.z; v.w *= v.w;
    *p = v;
}

extern "C" void kernel_launch(void* const* d_in, const int* in_sizes, int n_in,
                              void* d_out, int out_size, void* d_ws, size_t ws_size,
                              hipStream_t stream) {
    const float* coords     = (const float*)d_in[0];
    const float* shifts     = (const float*)d_in[1];
    const float* rs         = (const float*)d_in[2];
    const float* inta       = (const float*)d_in[3];
    const int*   atom_index = (const int*)d_in[6];
    const int*   species    = (const int*)d_in[7];
    float* out = (float*)d_out;

    if (ws_size >= WS2_NEEDED) {
        unsigned short* bucket = (unsigned short*)d_ws;
        unsigned char*  counts = (unsigned char*)d_ws + BUCKET_BYTES;

        radial_bin<<<dim3(NB * NSPLIT), dim3(BLOCK_A), 0, stream>>>(
            coords, shifts, atom_index, bucket, counts);
        radial_gather<<<dim3((TOTATOM * 4) / 256), dim3(256), 0, stream>>>(
            bucket, counts, rs, inta, species, out);
    } else {
        hipMemsetAsync(d_out, 0, (size_t)DENS_ELEMS * sizeof(float), stream);
        radial_pair_atomic<<<dim3((NPAIRS + 255) / 256), dim3(256), 0, stream>>>(
            coords, shifts, rs, inta, atom_index, species, out);
        square_kernel<<<dim3((DENS_ELEMS / 4 + 255) / 256), dim3(256), 0, stream>>>(out);
    }
}

// Round 11
// 55.343 us; speedup vs baseline: 10.0188x; 1.2244x over previous
//
#include <hip/hip_runtime.h>
#include <math.h>

// Problem constants (fixed by the reference setup)
#define NB     32
#define NA     1024
#define NTYPE  4
#define NWAVE  16
#define PPB    65536               // pairs per batch
#define NPAIRS (NB * PPB)          // 2,097,152 pairs
#define TOTATOM (NB * NA)          // 32768
#define DENS_ELEMS (TOTATOM * NTYPE * NWAVE)  // == out_size
#define CUTOFF      5.0f
#define CUTOFF_INV  0.2f
#define PI_F 3.14159265358979323846f

#define NSPLIT 8                   // bin blocks per batch
#define BLOCK_A 1024
#define PPBLK (PPB / NSPLIT)       // 8192 pairs per bin-block
#define KITERS_A (PPBLK / BLOCK_A) // 8
#define NSEG (NB * NSPLIT)         // 256 CSR segments
#define ENC_SCALE (65535.0f / CUTOFF)
#define DEC_SCALE (CUTOFF / 65535.0f)

#define CSR_BYTES  ((size_t)NSEG * PPBLK * 2)        // 4 MiB
#define OFFS_U32S  ((size_t)NSEG * (NA + 1))         // 262,400
#define WS2_NEEDED (CSR_BYTES + OFFS_U32S * 4)       // ~5.25 MB

// Compiler-visible native LDS u32 atomic add (returns old).
typedef __attribute__((address_space(3))) unsigned lds_u32;
__device__ __forceinline__ unsigned lds_uinc(unsigned* p) {
    lds_u32* lp = (lds_u32*)(unsigned)(unsigned long long)p;
    return __atomic_fetch_add(lp, 1u, __ATOMIC_RELAXED);
}

// ---------------------------------------------------------------------------
// Phase A: per (batch, split) block. Compute r once per pair (registers);
// LDS histogram atomic gives per-atom rank; block prefix-scan gives exact CSR
// bases; scatter u16-r inside LDS; stream to global fully coalesced.
// ---------------------------------------------------------------------------
__global__ __launch_bounds__(BLOCK_A) void radial_bin_csr(
    const float* __restrict__ coords,      // [TOTATOM*3]
    const float* __restrict__ shifts,      // [NPAIRS*3]
    const int*   __restrict__ atom_index,  // [NB*2*PPB]
    unsigned short* __restrict__ csr,      // [NSEG][PPBLK]
    unsigned*       __restrict__ offs)     // [NSEG][NA+1]
{
    __shared__ unsigned hist[NA];            // 4 KiB
    __shared__ unsigned base[NA + 1];        // 4 KiB
    __shared__ unsigned wsum[16];
    __shared__ unsigned short scsr[PPBLK];   // 16 KiB

    const int b    = blockIdx.x >> 3;        // / NSPLIT
    const int s    = blockIdx.x & (NSPLIT - 1);
    const int seg  = b * NSPLIT + s;
    const int tid  = threadIdx.x;
    const int lane = tid & 63;
    const int wid  = tid >> 6;

    hist[tid] = 0u;
    __syncthreads();

    const int* ai0 = atom_index + (b * 2 + 0) * PPB + s * PPBLK;
    const int* ai1 = atom_index + (b * 2 + 1) * PPB + s * PPBLK;
    const float* cb  = coords + (size_t)b * NA * 3;
    const float* shb = shifts + ((size_t)b * PPB + s * PPBLK) * 3;

    int      ik[KITERS_A];   // center atom, -1 if dropped
    unsigned ek[KITERS_A];   // (rank << 16) | quantized-r

    #pragma unroll
    for (int k = 0; k < KITERS_A; ++k) {
        const int pp = k * BLOCK_A + tid;
        const int i = ai0[pp];
        const int j = ai1[pp];

        const float sx = shb[pp * 3 + 0];
        const float sy = shb[pp * 3 + 1];
        const float sz = shb[pp * 3 + 2];
        const bool valid = (sx > -1e9f) && (sy > -1e9f) && (sz > -1e9f);

        const float dx = cb[i * 3 + 0] - cb[j * 3 + 0] + sx;
        const float dy = cb[i * 3 + 1] - cb[j * 3 + 1] + sy;
        const float dz = cb[i * 3 + 2] - cb[j * 3 + 2] + sz;
        const float r  = sqrtf(dx * dx + dy * dy + dz * dz);

        // r >= CUTOFF -> fc == 0 exactly: drop. invalid -> drop.
        if (valid && r < CUTOFF) {
            const unsigned rank = lds_uinc(&hist[i]);   // ds_add_rtn_u32
            unsigned e = (unsigned)(r * ENC_SCALE + 0.5f);
            if (e > 65535u) e = 65535u;
            ik[k] = i;
            ek[k] = (rank << 16) | e;
        } else {
            ik[k] = -1;
            ek[k] = 0u;
        }
    }
    __syncthreads();

    // Block-wide exclusive prefix scan of hist[1024].
    const unsigned h = hist[tid];
    unsigned x = h;
    #pragma unroll
    for (int d = 1; d < 64; d <<= 1) {
        const unsigned v = __shfl_up(x, d);
        if (lane >= d) x += v;
    }
    if (lane == 63) wsum[wid] = x;
    __syncthreads();
    if (tid < 16) {
        const unsigned own = wsum[tid];
        unsigned y = own;
        #pragma unroll
        for (int d = 1; d < 16; d <<= 1) {
            const unsigned v = __shfl_up(y, d);
            if (lane >= d) y += v;
        }
        wsum[tid] = y - own;     // exclusive wave prefix
    }
    __syncthreads();
    const unsigned incl = x + wsum[wid];
    base[tid] = incl - h;        // exclusive base for atom `tid`
    if (tid == BLOCK_A - 1) base[NA] = incl;   // total survivors
    __syncthreads();

    // Pass 2: place each pair at base[atom] + rank inside LDS CSR.
    #pragma unroll
    for (int k = 0; k < KITERS_A; ++k) {
        if (ik[k] >= 0) {
            const unsigned slot = base[ik[k]] + (ek[k] >> 16);
            scsr[slot] = (unsigned short)(ek[k] & 0xFFFFu);
        }
    }
    __syncthreads();

    // Stream out: 16 KiB CSR payload (coalesced uint4) + 1025 offsets.
    {
        const uint4* src = reinterpret_cast<const uint4*>(scsr);
        uint4* dst = reinterpret_cast<uint4*>(csr + (size_t)seg * PPBLK);
        dst[tid] = src[tid];     // 1024 threads x 16 B = 16 KiB
    }
    unsigned* og = offs + (size_t)seg * (NA + 1);
    og[tid] = base[tid];
    if (tid == 0) og[NA] = base[NA];
}

// ---------------------------------------------------------------------------
// Phase B: thread = (atom, w-quad). Walk the atom's 8 CSR segments, register
// accumulation, square, write the full 64-float output row. No atomics.
// ---------------------------------------------------------------------------
__global__ __launch_bounds__(256) void radial_gather_csr(
    const unsigned short* __restrict__ csr,   // [NSEG][PPBLK]
    const unsigned*       __restrict__ offs,  // [NSEG][NA+1]
    const float* __restrict__ rs,             // [NTYPE*NWAVE]
    const float* __restrict__ inta,           // [NTYPE*NWAVE]
    const int*   __restrict__ species,        // [TOTATOM]
    float*       __restrict__ out)            // [TOTATOM][NTYPE*NWAVE]
{
    const int t = blockIdx.x * blockDim.x + threadIdx.x;
    if (t >= TOTATOM * 4) return;
    const int g = t >> 2;              // global atom
    const int q = t & 3;               // w-quad
    const int b = g >> 10;             // batch
    const int a = g & (NA - 1);        // local atom

    const int spec = species[g];

    const float4 RS  = *reinterpret_cast<const float4*>(rs   + (spec << 4) + (q << 2));
    const float4 IAv = *reinterpret_cast<const float4*>(inta + (spec << 4) + (q << 2));
    const float ia0 = -10.0f * IAv.x, ia1 = -10.0f * IAv.y;
    const float ia2 = -10.0f * IAv.z, ia3 = -10.0f * IAv.w;

    float acc0 = 0.0f, acc1 = 0.0f, acc2 = 0.0f, acc3 = 0.0f;

    #pragma unroll
    for (int s = 0; s < NSPLIT; ++s) {
        const int seg = b * NSPLIT + s;
        const unsigned* ob = offs + (size_t)seg * (NA + 1) + a;
        const unsigned lo = ob[0];
        const unsigned hi = ob[1];
        const unsigned short* bp = csr + (size_t)seg * PPBLK;
        for (unsigned k = lo; k < hi; ++k) {
            const float r = (float)bp[k] * DEC_SCALE;
            const float x = fminf(r * CUTOFF_INV, 1.0f);
            float fc = 0.5f * (__cosf(x * PI_F) + 1.0f);
            fc = fmaxf(fc, 0.0f);
            const float lfc = __logf(fc);
            const float d0 = r - RS.x;
            const float d1 = r - RS.y;
            const float d2 = r - RS.z;
            const float d3 = r - RS.w;
            acc0 += __expf(fmaf(ia0 * d0, d0, lfc));
            acc1 += __expf(fmaf(ia1 * d1, d1, lfc));
            acc2 += __expf(fmaf(ia2 * d2, d2, lfc));
            acc3 += __expf(fmaf(ia3 * d3, d3, lfc));
        }
    }

    const float4 sq = make_float4(acc0 * acc0, acc1 * acc1,
                                  acc2 * acc2, acc3 * acc3);
    const float4 zero = make_float4(0.f, 0.f, 0.f, 0.f);
    float* orow = out + (size_t)g * (NTYPE * NWAVE) + (q << 2);
    #pragma unroll
    for (int ty = 0; ty < NTYPE; ++ty)
        *reinterpret_cast<float4*>(orow + ty * NWAVE) = (ty == spec) ? sq : zero;
}

// ---------------------------------------------------------------------------
// Fallback path (ws too small): global-atomic version (no workspace needed).
// ---------------------------------------------------------------------------
__global__ __launch_bounds__(256) void radial_pair_atomic(
    const float* __restrict__ coords, const float* __restrict__ shifts,
    const float* __restrict__ rs, const float* __restrict__ inta,
    const int* __restrict__ atom_index, const int* __restrict__ species,
    float* __restrict__ dens)
{
    int p = blockIdx.x * blockDim.x + threadIdx.x;
    if (p >= NPAIRS) return;
    int b  = p >> 16;
    int pp = p & (PPB - 1);
    int i = atom_index[(b * 2 + 0) * PPB + pp] + b * NA;
    int j = atom_index[(b * 2 + 1) * PPB + pp] + b * NA;
    float sx = shifts[p * 3 + 0], sy = shifts[p * 3 + 1], sz = shifts[p * 3 + 2];
    bool valid = (sx > -1e9f) && (sy > -1e9f) && (sz > -1e9f);
    float dx = coords[i * 3 + 0] - coords[j * 3 + 0] + sx;
    float dy = coords[i * 3 + 1] - coords[j * 3 + 1] + sy;
    float dz = coords[i * 3 + 2] - coords[j * 3 + 2] + sz;
    float r  = sqrtf(dx * dx + dy * dy + dz * dz);
    int spec = species[i];
    float x  = fminf(r * CUTOFF_INV, 1.0f);
    float fc = 0.5f * (__cosf(x * PI_F) + 1.0f);
    if (!valid) fc = 0.0f;
    const float* rsrow   = rs   + spec * NWAVE;
    const float* intarow = inta + spec * NWAVE;
    float* dst = dens + ((size_t)i * NTYPE + spec) * NWAVE;
    #pragma unroll
    for (int w = 0; w < NWAVE; ++w) {
        float d   = r - rsrow[w];
        float val = fc * __expf(-10.0f * intarow[w] * d * d);
        atomicAdd(dst + w, val);
    }
}

__global__ __launch_bounds__(256) void square_kernel(float* __restrict__ out)
{
    int i = blockIdx.x * blockDim.x + threadIdx.x;
    if (i * 4 >= DENS_ELEMS) return;
    float4* p = reinterpret_cast<float4*>(out) + i;
    float4 v = *p;
    v.x *= v.x; v.y *= v.y; v.z *= v.z; v.w *= v.w;
    *p = v;
}

extern "C" void kernel_launch(void* const* d_in, const int* in_sizes, int n_in,
                              void* d_out, int out_size, void* d_ws, size_t ws_size,
                              hipStream_t stream) {
    const float* coords     = (const float*)d_in[0];
    const float* shifts     = (const float*)d_in[1];
    const float* rs         = (const float*)d_in[2];
    const float* inta       = (const float*)d_in[3];
    const int*   atom_index = (const int*)d_in[6];
    const int*   species    = (const int*)d_in[7];
    float* out = (float*)d_out;

    if (ws_size >= WS2_NEEDED) {
        unsigned short* csr  = (unsigned short*)d_ws;
        unsigned*       offs = (unsigned*)((char*)d_ws + CSR_BYTES);

        radial_bin_csr<<<dim3(NSEG), dim3(BLOCK_A), 0, stream>>>(
            coords, shifts, atom_index, csr, offs);
        radial_gather_csr<<<dim3((TOTATOM * 4) / 256), dim3(256), 0, stream>>>(
            csr, offs, rs, inta, species, out);
    } else {
        hipMemsetAsync(d_out, 0, (size_t)DENS_ELEMS * sizeof(float), stream);
        radial_pair_atomic<<<dim3((NPAIRS + 255) / 256), dim3(256), 0, stream>>>(
            coords, shifts, rs, inta, atom_index, species, out);
        square_kernel<<<dim3((DENS_ELEMS / 4 + 255) / 256), dim3(256), 0, stream>>>(out);
    }
}

// Round 12
// 52.283 us; speedup vs baseline: 10.6052x; 1.0585x over previous
//
#include <hip/hip_runtime.h>
#include <math.h>

// Problem constants (fixed by the reference setup)
#define NB     32
#define NA     1024
#define NTYPE  4
#define NWAVE  16
#define PPB    65536               // pairs per batch
#define NPAIRS (NB * PPB)          // 2,097,152 pairs
#define TOTATOM (NB * NA)          // 32768
#define DENS_ELEMS (TOTATOM * NTYPE * NWAVE)  // == out_size
#define CUTOFF      5.0f
#define CUTOFF_INV  0.2f
#define PI_F 3.14159265358979323846f

#define NSPLIT 8                   // bin blocks per batch
#define BLOCK_A 1024
#define PPBLK (PPB / NSPLIT)       // 8192 pairs per bin-block
#define KITERS_A (PPBLK / BLOCK_A) // 8
#define NSEG (NB * NSPLIT)         // 256 CSR segments
#define ENC_SCALE (65535.0f / CUTOFF)
#define DEC_SCALE (CUTOFF / 65535.0f)
#define LMAX 24.0f                 // |lfc| <= 21.4 for r < cutoff
#define LENC (65535.0f / LMAX)
#define LDEC (LMAX / 65535.0f)

#define CSR_BYTES  ((size_t)NSEG * PPBLK * 4)        // 8 MiB (packed u32)
#define OFFS_U32S  ((size_t)NSEG * (NA + 1))         // 262,400
#define WS2_NEEDED (CSR_BYTES + OFFS_U32S * 4)       // ~9.4 MB

// Compiler-visible native LDS u32 atomic add (returns old).
typedef __attribute__((address_space(3))) unsigned lds_u32;
__device__ __forceinline__ unsigned lds_uinc(unsigned* p) {
    lds_u32* lp = (lds_u32*)(unsigned)(unsigned long long)p;
    return __atomic_fetch_add(lp, 1u, __ATOMIC_RELAXED);
}

// ---------------------------------------------------------------------------
// Phase A: per (batch, split) block. Compute r and lfc=log(fc(r)) once per
// pair; LDS histogram atomic gives per-atom rank; block prefix-scan gives
// exact CSR bases; scatter packed (lfc_u16|r_u16) inside LDS; stream out
// fully coalesced.
// ---------------------------------------------------------------------------
__global__ __launch_bounds__(BLOCK_A) void radial_bin_csr(
    const float* __restrict__ coords,      // [TOTATOM*3]
    const float* __restrict__ shifts,      // [NPAIRS*3]
    const int*   __restrict__ atom_index,  // [NB*2*PPB]
    unsigned*    __restrict__ csr,         // [NSEG][PPBLK] packed
    unsigned*    __restrict__ offs)        // [NSEG][NA+1]
{
    __shared__ unsigned hist[NA];            // 4 KiB
    __shared__ unsigned base[NA + 1];        // 4 KiB
    __shared__ unsigned wsum[16];
    __shared__ unsigned scsr[PPBLK];         // 32 KiB

    const int b    = blockIdx.x >> 3;        // / NSPLIT
    const int s    = blockIdx.x & (NSPLIT - 1);
    const int seg  = b * NSPLIT + s;
    const int tid  = threadIdx.x;
    const int lane = tid & 63;
    const int wid  = tid >> 6;

    hist[tid] = 0u;
    __syncthreads();

    const int* ai0 = atom_index + (b * 2 + 0) * PPB + s * PPBLK;
    const int* ai1 = atom_index + (b * 2 + 1) * PPB + s * PPBLK;
    const float* cb  = coords + (size_t)b * NA * 3;
    const float* shb = shifts + ((size_t)b * PPB + s * PPBLK) * 3;

    int      ik[KITERS_A];   // center atom, -1 if dropped
    unsigned rk[KITERS_A];   // rank from histogram atomic
    unsigned ek[KITERS_A];   // packed (lfc_u16 << 16) | r_u16

    #pragma unroll
    for (int k = 0; k < KITERS_A; ++k) {
        const int pp = k * BLOCK_A + tid;
        const int i = ai0[pp];
        const int j = ai1[pp];

        const float sx = shb[pp * 3 + 0];
        const float sy = shb[pp * 3 + 1];
        const float sz = shb[pp * 3 + 2];
        const bool valid = (sx > -1e9f) && (sy > -1e9f) && (sz > -1e9f);

        const float dx = cb[i * 3 + 0] - cb[j * 3 + 0] + sx;
        const float dy = cb[i * 3 + 1] - cb[j * 3 + 1] + sy;
        const float dz = cb[i * 3 + 2] - cb[j * 3 + 2] + sz;
        const float r  = sqrtf(dx * dx + dy * dy + dz * dz);

        // r >= CUTOFF -> fc == 0 exactly: drop. invalid -> drop.
        if (valid && r < CUTOFF) {
            const unsigned rank = lds_uinc(&hist[i]);   // ds_add_rtn_u32
            unsigned e = (unsigned)(r * ENC_SCALE + 0.5f);
            if (e > 65535u) e = 65535u;
            // fc > 0 strictly here (r < cutoff); lfc in [-21.4, 0]
            float fc = 0.5f * (__cosf(fminf(r * CUTOFF_INV, 1.0f) * PI_F) + 1.0f);
            fc = fmaxf(fc, 1e-30f);
            const float lfc = __logf(fc);
            unsigned lq = (unsigned)(lfc * -LENC + 0.5f);
            if (lq > 65535u) lq = 65535u;
            ik[k] = i;
            rk[k] = rank;
            ek[k] = (lq << 16) | e;
        } else {
            ik[k] = -1;
            rk[k] = 0u;
            ek[k] = 0u;
        }
    }
    __syncthreads();

    // Block-wide exclusive prefix scan of hist[1024].
    const unsigned h = hist[tid];
    unsigned x = h;
    #pragma unroll
    for (int d = 1; d < 64; d <<= 1) {
        const unsigned v = __shfl_up(x, d);
        if (lane >= d) x += v;
    }
    if (lane == 63) wsum[wid] = x;
    __syncthreads();
    if (tid < 16) {
        const unsigned own = wsum[tid];
        unsigned y = own;
        #pragma unroll
        for (int d = 1; d < 16; d <<= 1) {
            const unsigned v = __shfl_up(y, d);
            if (lane >= d) y += v;
        }
        wsum[tid] = y - own;     // exclusive wave prefix
    }
    __syncthreads();
    const unsigned incl = x + wsum[wid];
    base[tid] = incl - h;        // exclusive base for atom `tid`
    if (tid == BLOCK_A - 1) base[NA] = incl;   // total survivors
    __syncthreads();

    // Pass 2: place each pair at base[atom] + rank inside LDS CSR.
    #pragma unroll
    for (int k = 0; k < KITERS_A; ++k) {
        if (ik[k] >= 0) {
            scsr[base[ik[k]] + rk[k]] = ek[k];
        }
    }
    __syncthreads();

    // Stream out: 32 KiB CSR payload (coalesced uint4) + 1025 offsets.
    {
        const uint4* src = reinterpret_cast<const uint4*>(scsr);
        uint4* dst = reinterpret_cast<uint4*>(csr + (size_t)seg * PPBLK);
        #pragma unroll
        for (int k = 0; k < PPBLK / 4 / BLOCK_A; ++k)
            dst[k * BLOCK_A + tid] = src[k * BLOCK_A + tid];
    }
    unsigned* og = offs + (size_t)seg * (NA + 1);
    og[tid] = base[tid];
    if (tid == 0) og[NA] = base[NA];
}

// ---------------------------------------------------------------------------
// Phase B: thread = (atom, w). The 16 threads of an atom read the same CSR
// words (same-address broadcast). Per entry: load -> fma -> exp -> add.
// No atomics, no cos/log (precomputed lfc).
// ---------------------------------------------------------------------------
__global__ __launch_bounds__(256) void radial_gather16(
    const unsigned* __restrict__ csr,    // [NSEG][PPBLK] packed
    const unsigned* __restrict__ offs,   // [NSEG][NA+1]
    const float* __restrict__ rs,        // [NTYPE*NWAVE]
    const float* __restrict__ inta,      // [NTYPE*NWAVE]
    const int*   __restrict__ species,   // [TOTATOM]
    float*       __restrict__ out)       // [TOTATOM][NTYPE*NWAVE]
{
    const int t = blockIdx.x * blockDim.x + threadIdx.x;
    if (t >= TOTATOM * NWAVE) return;
    const int g = t >> 4;              // global atom
    const int w = t & (NWAVE - 1);     // wave index
    const int b = g >> 10;             // batch
    const int a = g & (NA - 1);        // local atom

    const int spec = species[g];
    const float rs_w = rs[(spec << 4) + w];
    const float ia_w = -10.0f * inta[(spec << 4) + w];

    float acc = 0.0f;

    #pragma unroll
    for (int s = 0; s < NSPLIT; ++s) {
        const int seg = b * NSPLIT + s;
        const unsigned* ob = offs + (size_t)seg * (NA + 1) + a;
        const unsigned lo = ob[0];
        const unsigned hi = ob[1];
        const unsigned* bp = csr + (size_t)seg * PPBLK;
        for (unsigned k = lo; k < hi; ++k) {
            const unsigned v = bp[k];
            const float r   = (float)(v & 0xFFFFu) * DEC_SCALE;
            const float lfc = (float)(v >> 16) * -LDEC;
            const float d = r - rs_w;
            acc += __expf(fmaf(ia_w * d, d, lfc));
        }
    }

    const float res = acc * acc;
    float* orow = out + (size_t)g * (NTYPE * NWAVE) + w;
    #pragma unroll
    for (int ty = 0; ty < NTYPE; ++ty)
        orow[ty * NWAVE] = (ty == spec) ? res : 0.0f;
}

// ---------------------------------------------------------------------------
// Fallback path (ws too small): global-atomic version (no workspace needed).
// ---------------------------------------------------------------------------
__global__ __launch_bounds__(256) void radial_pair_atomic(
    const float* __restrict__ coords, const float* __restrict__ shifts,
    const float* __restrict__ rs, const float* __restrict__ inta,
    const int* __restrict__ atom_index, const int* __restrict__ species,
    float* __restrict__ dens)
{
    int p = blockIdx.x * blockDim.x + threadIdx.x;
    if (p >= NPAIRS) return;
    int b  = p >> 16;
    int pp = p & (PPB - 1);
    int i = atom_index[(b * 2 + 0) * PPB + pp] + b * NA;
    int j = atom_index[(b * 2 + 1) * PPB + pp] + b * NA;
    float sx = shifts[p * 3 + 0], sy = shifts[p * 3 + 1], sz = shifts[p * 3 + 2];
    bool valid = (sx > -1e9f) && (sy > -1e9f) && (sz > -1e9f);
    float dx = coords[i * 3 + 0] - coords[j * 3 + 0] + sx;
    float dy = coords[i * 3 + 1] - coords[j * 3 + 1] + sy;
    float dz = coords[i * 3 + 2] - coords[j * 3 + 2] + sz;
    float r  = sqrtf(dx * dx + dy * dy + dz * dz);
    int spec = species[i];
    float x  = fminf(r * CUTOFF_INV, 1.0f);
    float fc = 0.5f * (__cosf(x * PI_F) + 1.0f);
    if (!valid) fc = 0.0f;
    const float* rsrow   = rs   + spec * NWAVE;
    const float* intarow = inta + spec * NWAVE;
    float* dst = dens + ((size_t)i * NTYPE + spec) * NWAVE;
    #pragma unroll
    for (int w = 0; w < NWAVE; ++w) {
        float d   = r - rsrow[w];
        float val = fc * __expf(-10.0f * intarow[w] * d * d);
        atomicAdd(dst + w, val);
    }
}

__global__ __launch_bounds__(256) void square_kernel(float* __restrict__ out)
{
    int i = blockIdx.x * blockDim.x + threadIdx.x;
    if (i * 4 >= DENS_ELEMS) return;
    float4* p = reinterpret_cast<float4*>(out) + i;
    float4 v = *p;
    v.x *= v.x; v.y *= v.y; v.z *= v.z; v.w *= v.w;
    *p = v;
}

extern "C" void kernel_launch(void* const* d_in, const int* in_sizes, int n_in,
                              void* d_out, int out_size, void* d_ws, size_t ws_size,
                              hipStream_t stream) {
    const float* coords     = (const float*)d_in[0];
    const float* shifts     = (const float*)d_in[1];
    const float* rs         = (const float*)d_in[2];
    const float* inta       = (const float*)d_in[3];
    const int*   atom_index = (const int*)d_in[6];
    const int*   species    = (const int*)d_in[7];
    float* out = (float*)d_out;

    if (ws_size >= WS2_NEEDED) {
        unsigned* csr  = (unsigned*)d_ws;
        unsigned* offs = (unsigned*)((char*)d_ws + CSR_BYTES);

        radial_bin_csr<<<dim3(NSEG), dim3(BLOCK_A), 0, stream>>>(
            coords, shifts, atom_index, csr, offs);
        radial_gather16<<<dim3((TOTATOM * NWAVE) / 256), dim3(256), 0, stream>>>(
            csr, offs, rs, inta, species, out);
    } else {
        hipMemsetAsync(d_out, 0, (size_t)DENS_ELEMS * sizeof(float), stream);
        radial_pair_atomic<<<dim3((NPAIRS + 255) / 256), dim3(256), 0, stream>>>(
            coords, shifts, rs, inta, atom_index, species, out);
        square_kernel<<<dim3((DENS_ELEMS / 4 + 255) / 256), dim3(256), 0, stream>>>(out);
    }
}

// Round 13
// 33.645 us; speedup vs baseline: 16.4799x; 1.5539x over previous
//
#include <hip/hip_runtime.h>
#include <math.h>

// Problem constants (fixed by the reference setup)
#define NB     32
#define NA     1024
#define NTYPE  4
#define NWAVE  16
#define PPB    65536               // pairs per batch
#define NPAIRS (NB * PPB)          // 2,097,152 pairs
#define TOTATOM (NB * NA)          // 32768
#define DENS_ELEMS (TOTATOM * NTYPE * NWAVE)  // == out_size
#define CUTOFF      5.0f
#define CUTOFF_INV  0.2f
#define PI_F 3.14159265358979323846f

#define NSPLIT 8                   // bin blocks per batch
#define BLOCK_A 1024
#define PPBLK (PPB / NSPLIT)       // 8192 pairs per bin-block
#define KITERS_A (PPBLK / BLOCK_A) // 8
#define NSEG (NB * NSPLIT)         // 256 CSR segments
#define ENC_SCALE (65535.0f / CUTOFF)
#define DEC_SCALE (CUTOFF / 65535.0f)
#define LMAX 24.0f                 // |lfc| <= 21.4 for r < cutoff
#define LENC (65535.0f / LMAX)
#define LDEC (LMAX / 65535.0f)

#define CSR_BYTES  ((size_t)NSEG * PPBLK * 4)        // 8 MiB (packed u32)
#define OFFS_U32S  ((size_t)NSEG * (NA + 1))         // 262,400
#define WS2_NEEDED (CSR_BYTES + OFFS_U32S * 4)       // ~9.4 MB

// Gather geometry
#define GBLOCK 256
#define APB    16                  // atoms per gather block
#define ACAP   152                 // per-atom staging cap (mean 61.3; P(>152)~1e-21)

// Compiler-visible native LDS u32 atomic add (returns old).
typedef __attribute__((address_space(3))) unsigned lds_u32;
__device__ __forceinline__ unsigned lds_uinc(unsigned* p) {
    lds_u32* lp = (lds_u32*)(unsigned)(unsigned long long)p;
    return __atomic_fetch_add(lp, 1u, __ATOMIC_RELAXED);
}

// ---------------------------------------------------------------------------
// Phase A (unchanged from round 12): per (batch, split) block. r + lfc once
// per pair; LDS histogram rank; block prefix-scan -> exact CSR; coalesced out.
// ---------------------------------------------------------------------------
__global__ __launch_bounds__(BLOCK_A) void radial_bin_csr(
    const float* __restrict__ coords,      // [TOTATOM*3]
    const float* __restrict__ shifts,      // [NPAIRS*3]
    const int*   __restrict__ atom_index,  // [NB*2*PPB]
    unsigned*    __restrict__ csr,         // [NSEG][PPBLK] packed
    unsigned*    __restrict__ offs)        // [NSEG][NA+1]
{
    __shared__ unsigned hist[NA];            // 4 KiB
    __shared__ unsigned base[NA + 1];        // 4 KiB
    __shared__ unsigned wsum[16];
    __shared__ unsigned scsr[PPBLK];         // 32 KiB

    const int b    = blockIdx.x >> 3;        // / NSPLIT
    const int s    = blockIdx.x & (NSPLIT - 1);
    const int seg  = b * NSPLIT + s;
    const int tid  = threadIdx.x;
    const int lane = tid & 63;
    const int wid  = tid >> 6;

    hist[tid] = 0u;
    __syncthreads();

    const int* ai0 = atom_index + (b * 2 + 0) * PPB + s * PPBLK;
    const int* ai1 = atom_index + (b * 2 + 1) * PPB + s * PPBLK;
    const float* cb  = coords + (size_t)b * NA * 3;
    const float* shb = shifts + ((size_t)b * PPB + s * PPBLK) * 3;

    int      ik[KITERS_A];   // center atom, -1 if dropped
    unsigned rk[KITERS_A];   // rank from histogram atomic
    unsigned ek[KITERS_A];   // packed (lfc_u16 << 16) | r_u16

    #pragma unroll
    for (int k = 0; k < KITERS_A; ++k) {
        const int pp = k * BLOCK_A + tid;
        const int i = ai0[pp];
        const int j = ai1[pp];

        const float sx = shb[pp * 3 + 0];
        const float sy = shb[pp * 3 + 1];
        const float sz = shb[pp * 3 + 2];
        const bool valid = (sx > -1e9f) && (sy > -1e9f) && (sz > -1e9f);

        const float dx = cb[i * 3 + 0] - cb[j * 3 + 0] + sx;
        const float dy = cb[i * 3 + 1] - cb[j * 3 + 1] + sy;
        const float dz = cb[i * 3 + 2] - cb[j * 3 + 2] + sz;
        const float r  = sqrtf(dx * dx + dy * dy + dz * dz);

        // r >= CUTOFF -> fc == 0 exactly: drop. invalid -> drop.
        if (valid && r < CUTOFF) {
            const unsigned rank = lds_uinc(&hist[i]);   // ds_add_rtn_u32
            unsigned e = (unsigned)(r * ENC_SCALE + 0.5f);
            if (e > 65535u) e = 65535u;
            float fc = 0.5f * (__cosf(fminf(r * CUTOFF_INV, 1.0f) * PI_F) + 1.0f);
            fc = fmaxf(fc, 1e-30f);
            const float lfc = __logf(fc);
            unsigned lq = (unsigned)(lfc * -LENC + 0.5f);
            if (lq > 65535u) lq = 65535u;
            ik[k] = i;
            rk[k] = rank;
            ek[k] = (lq << 16) | e;
        } else {
            ik[k] = -1;
            rk[k] = 0u;
            ek[k] = 0u;
        }
    }
    __syncthreads();

    // Block-wide exclusive prefix scan of hist[1024].
    const unsigned h = hist[tid];
    unsigned x = h;
    #pragma unroll
    for (int d = 1; d < 64; d <<= 1) {
        const unsigned v = __shfl_up(x, d);
        if (lane >= d) x += v;
    }
    if (lane == 63) wsum[wid] = x;
    __syncthreads();
    if (tid < 16) {
        const unsigned own = wsum[tid];
        unsigned y = own;
        #pragma unroll
        for (int d = 1; d < 16; d <<= 1) {
            const unsigned v = __shfl_up(y, d);
            if (lane >= d) y += v;
        }
        wsum[tid] = y - own;     // exclusive wave prefix
    }
    __syncthreads();
    const unsigned incl = x + wsum[wid];
    base[tid] = incl - h;
    if (tid == BLOCK_A - 1) base[NA] = incl;
    __syncthreads();

    // Pass 2: place each pair at base[atom] + rank inside LDS CSR.
    #pragma unroll
    for (int k = 0; k < KITERS_A; ++k) {
        if (ik[k] >= 0) {
            scsr[base[ik[k]] + rk[k]] = ek[k];
        }
    }
    __syncthreads();

    // Stream out coalesced.
    {
        const uint4* src = reinterpret_cast<const uint4*>(scsr);
        uint4* dst = reinterpret_cast<uint4*>(csr + (size_t)seg * PPBLK);
        #pragma unroll
        for (int k = 0; k < PPBLK / 4 / BLOCK_A; ++k)
            dst[k * BLOCK_A + tid] = src[k * BLOCK_A + tid];
    }
    unsigned* og = offs + (size_t)seg * (NA + 1);
    og[tid] = base[tid];
    if (tid == 0) og[NA] = base[NA];
}

// ---------------------------------------------------------------------------
// Phase B: LDS-staged gather. Block = 16 atoms x 16 w. Staging threads
// (atom,seg) concatenate the atom's 8 segments into LDS as decoded (r,lfc)
// float2; compute threads run ONE loop over the atom's full entry list with
// ds_read broadcast. No per-segment dependent chains, minimal divergence.
// ---------------------------------------------------------------------------
__global__ __launch_bounds__(GBLOCK) void radial_gather_staged(
    const unsigned* __restrict__ csr,    // [NSEG][PPBLK] packed
    const unsigned* __restrict__ offs,   // [NSEG][NA+1]
    const float* __restrict__ rs,        // [NTYPE*NWAVE]
    const float* __restrict__ inta,      // [NTYPE*NWAVE]
    const int*   __restrict__ species,   // [TOTATOM]
    float*       __restrict__ out)       // [TOTATOM][NTYPE*NWAVE]
{
    __shared__ float2   sdata[APB * ACAP];   // 19.0 KiB decoded entries
    __shared__ unsigned scnt[APB];

    const int tid = threadIdx.x;
    const int g0  = blockIdx.x * APB;        // first atom of block
    const int b   = g0 >> 10;                // batch (blocks never cross batches)

    // ---- Staging: tid 0..127 -> (at, s) ----
    if (tid < APB * NSPLIT) {
        const int at = tid >> 3;
        const int s  = tid & 7;
        const int a  = (g0 + at) & (NA - 1);
        const int seg = b * NSPLIT + s;
        const unsigned* ob = offs + (size_t)seg * (NA + 1) + a;
        const unsigned lo = ob[0];
        const unsigned c  = ob[1] - lo;

        // inclusive scan of c over the 8 segment-lanes of this atom
        unsigned x = c;
        #pragma unroll
        for (int d = 1; d < 8; d <<= 1) {
            const unsigned v = __shfl_up(x, d, 8);
            if ((tid & 7) >= d) x += v;
        }
        const unsigned pfx = x - c;          // exclusive prefix
        if ((tid & 7) == 7) scnt[at] = (x < ACAP) ? x : ACAP;

        const unsigned* bp = csr + (size_t)seg * PPBLK + lo;
        float2* dst = sdata + at * ACAP;
        for (unsigned k = 0; k < c; ++k) {
            const unsigned p = pfx + k;
            if (p < ACAP) {
                const unsigned v = bp[k];
                float2 e;
                e.x = (float)(v & 0xFFFFu) * DEC_SCALE;   // r
                e.y = (float)(v >> 16) * -LDEC;           // lfc
                dst[p] = e;
            }
        }
    }
    __syncthreads();

    // ---- Compute: (at, w) ----
    const int at = tid >> 4;
    const int w  = tid & (NWAVE - 1);
    const int g  = g0 + at;
    const int spec = species[g];

    const float rs_w = rs[(spec << 4) + w];
    const float ia_w = -10.0f * inta[(spec << 4) + w];
    const int n = (int)scnt[at];
    const float2* sp = sdata + at * ACAP;

    float acc = 0.0f;
    for (int k = 0; k < n; ++k) {
        const float2 e = sp[k];              // 16-lane same-address broadcast
        const float d = e.x - rs_w;
        acc += __expf(fmaf(ia_w * d, d, e.y));
    }

    const float res = acc * acc;
    float* orow = out + (size_t)g * (NTYPE * NWAVE) + w;
    #pragma unroll
    for (int ty = 0; ty < NTYPE; ++ty)
        orow[ty * NWAVE] = (ty == spec) ? res : 0.0f;
}

// ---------------------------------------------------------------------------
// Fallback path (ws too small): global-atomic version (no workspace needed).
// ---------------------------------------------------------------------------
__global__ __launch_bounds__(256) void radial_pair_atomic(
    const float* __restrict__ coords, const float* __restrict__ shifts,
    const float* __restrict__ rs, const float* __restrict__ inta,
    const int* __restrict__ atom_index, const int* __restrict__ species,
    float* __restrict__ dens)
{
    int p = blockIdx.x * blockDim.x + threadIdx.x;
    if (p >= NPAIRS) return;
    int b  = p >> 16;
    int pp = p & (PPB - 1);
    int i = atom_index[(b * 2 + 0) * PPB + pp] + b * NA;
    int j = atom_index[(b * 2 + 1) * PPB + pp] + b * NA;
    float sx = shifts[p * 3 + 0], sy = shifts[p * 3 + 1], sz = shifts[p * 3 + 2];
    bool valid = (sx > -1e9f) && (sy > -1e9f) && (sz > -1e9f);
    float dx = coords[i * 3 + 0] - coords[j * 3 + 0] + sx;
    float dy = coords[i * 3 + 1] - coords[j * 3 + 1] + sy;
    float dz = coords[i * 3 + 2] - coords[j * 3 + 2] + sz;
    float r  = sqrtf(dx * dx + dy * dy + dz * dz);
    int spec = species[i];
    float x  = fminf(r * CUTOFF_INV, 1.0f);
    float fc = 0.5f * (__cosf(x * PI_F) + 1.0f);
    if (!valid) fc = 0.0f;
    const float* rsrow   = rs   + spec * NWAVE;
    const float* intarow = inta + spec * NWAVE;
    float* dst = dens + ((size_t)i * NTYPE + spec) * NWAVE;
    #pragma unroll
    for (int w = 0; w < NWAVE; ++w) {
        float d   = r - rsrow[w];
        float val = fc * __expf(-10.0f * intarow[w] * d * d);
        atomicAdd(dst + w, val);
    }
}

__global__ __launch_bounds__(256) void square_kernel(float* __restrict__ out)
{
    int i = blockIdx.x * blockDim.x + threadIdx.x;
    if (i * 4 >= DENS_ELEMS) return;
    float4* p = reinterpret_cast<float4*>(out) + i;
    float4 v = *p;
    v.x *= v.x; v.y *= v.y; v.z *= v.z; v.w *= v.w;
    *p = v;
}

extern "C" void kernel_launch(void* const* d_in, const int* in_sizes, int n_in,
                              void* d_out, int out_size, void* d_ws, size_t ws_size,
                              hipStream_t stream) {
    const float* coords     = (const float*)d_in[0];
    const float* shifts     = (const float*)d_in[1];
    const float* rs         = (const float*)d_in[2];
    const float* inta       = (const float*)d_in[3];
    const int*   atom_index = (const int*)d_in[6];
    const int*   species    = (const int*)d_in[7];
    float* out = (float*)d_out;

    if (ws_size >= WS2_NEEDED) {
        unsigned* csr  = (unsigned*)d_ws;
        unsigned* offs = (unsigned*)((char*)d_ws + CSR_BYTES);

        radial_bin_csr<<<dim3(NSEG), dim3(BLOCK_A), 0, stream>>>(
            coords, shifts, atom_index, csr, offs);
        radial_gather_staged<<<dim3(TOTATOM / APB), dim3(GBLOCK), 0, stream>>>(
            csr, offs, rs, inta, species, out);
    } else {
        hipMemsetAsync(d_out, 0, (size_t)DENS_ELEMS * sizeof(float), stream);
        radial_pair_atomic<<<dim3((NPAIRS + 255) / 256), dim3(256), 0, stream>>>(
            coords, shifts, rs, inta, atom_index, species, out);
        square_kernel<<<dim3((DENS_ELEMS / 4 + 255) / 256), dim3(256), 0, stream>>>(out);
    }
}